// Round 8
// baseline (110.117 us; speedup 1.0000x reference)
//
#include <hip/hip_runtime.h>
#include <hip/hip_bf16.h>

// Problem constants (from reference): B=8, S=1024, E=64, H=8, DK=8
#define BB 8
#define SS 1024
#define EE 64
#define HH 8
#define DKW 8

typedef __hip_bfloat16 bf16;
typedef unsigned short u16;
typedef _Float16 half8v __attribute__((ext_vector_type(8)));
typedef float floatx4 __attribute__((ext_vector_type(4)));

#define MFMA16(a, b, c) __builtin_amdgcn_mfma_f32_16x16x32_f16(a, b, c, 0, 0, 0)

// ---------------------------------------------------------------------------
// Block-uniform dtype self-detection (R4-R7 proven): if `base` really holds
// float32, even-indexed u16s are random f32 mantissa bits -> ~48% decode (as
// bf16) to |v| >= 32; genuine bf16 N(0,1) -> ~0. Deterministic per buffer.
template <int NT>
__device__ __forceinline__ bool detect_f32(const u16* __restrict__ base,
                                           int tid, int* red) {
    int cnt = 0;
    for (int i = tid; i < 2048; i += NT) {
        u16 u = base[i * 2];
        int ex = (u >> 7) & 0xFF;
        cnt += (ex >= 0x84) ? 1 : 0;
    }
#pragma unroll
    for (int off = 32; off > 0; off >>= 1) cnt += __shfl_xor(cnt, off, 64);
    if ((tid & 63) == 0) red[tid >> 6] = cnt;
    __syncthreads();
    int tot = 0;
#pragma unroll
    for (int w = 0; w < NT / 64; ++w) tot += red[w];
    return tot > 64;
}

// ---------------------------------------------------------------------------
// Analytic quantum projection (R0 derivation, verified R2-R7):
//   Z_0 = prod_{j=1..7} cos(theta_j);  Z_w = prod_{j=0..w} cos(theta_j)
// m = (b*S + s)*H + h ; writes z[0..7] for e = h*8..h*8+7.
__device__ __forceinline__ void proj_compute(const void* x, const void* phi,
                                             bool f32, int m, float* z) {
    int h = m & (HH - 1);
    float th[DKW];
    if (f32) {
        const float4* xp = (const float4*)((const float*)x + (size_t)m * DKW);
        const float4* pp = (const float4*)((const float*)phi + h * DKW);
        float4 x0 = xp[0], x1 = xp[1];
        float4 p0 = pp[0], p1 = pp[1];
        th[0] = x0.x + p0.x; th[1] = x0.y + p0.y; th[2] = x0.z + p0.z; th[3] = x0.w + p0.w;
        th[4] = x1.x + p1.x; th[5] = x1.y + p1.y; th[6] = x1.z + p1.z; th[7] = x1.w + p1.w;
    } else {
        union { uint4 u; bf16 hv[8]; } xu, pu;
        xu.u = *(const uint4*)((const bf16*)x + (size_t)m * DKW);
        pu.u = *(const uint4*)((const bf16*)phi + (size_t)h * DKW);
#pragma unroll
        for (int j = 0; j < DKW; ++j)
            th[j] = __bfloat162float(xu.hv[j]) + __bfloat162float(pu.hv[j]);
    }
    float c[DKW];
#pragma unroll
    for (int j = 0; j < DKW; ++j) c[j] = __cosf(th[j]);
    float suf = c[1];
#pragma unroll
    for (int j = 2; j < DKW; ++j) suf *= c[j];
    z[0] = suf;
    float pre = c[0];
#pragma unroll
    for (int w = 1; w < DKW; ++w) { pre *= c[w]; z[w] = pre; }
}

// Stile: flat 16x1024 fp16, XOR-swizzled (R5-proven): A-frag b128 reads land
// 2 lanes/bank (free); swizzle is a within-row permutation (softmax-safe).
__device__ __forceinline__ int sidx(int row, int colblk) {
    return row * 1024 + ((colblk ^ (row & 7)) << 3);
}

// ---------------------------------------------------------------------------
// Single self-contained kernel. Block = 16 q-rows of one batch. NO global
// intermediates: z-values recomputed per chunk into LDS (cheap: 8 cos).
// Grid 512 (1-D): b = bid & 7 pins each batch to one XCD (bid%8 round-robin)
// so each XCD only touches its own 1 MB x-slab -> L2-resident.
__global__ __launch_bounds__(512, 2) void qflash(const void* __restrict__ x,
                                                 const void* __restrict__ phi,
                                                 const void* __restrict__ Wp,
                                                 const void* __restrict__ biasp,
                                                 void* __restrict__ outp) {
    __shared__ _Float16 KV[8192];          // 16 KB chunk stage (K / V layouts)
    __shared__ _Float16 Stile[16 * 1024];  // 32 KB swizzled score tile
    __shared__ float    pacc[4][16][17];
    __shared__ _Float16 ctx_lds[16][72];
    __shared__ float    rowsum[16];
    __shared__ int      redd[8];

    const int tid = threadIdx.x;
    const int wave = tid >> 6, lane = tid & 63;
    const int lr = lane & 15, quad = lane >> 4;
    const int bid = blockIdx.x;
    const int b = bid & 7;                 // XCD-pinned batch
    const int m0 = (bid >> 3) * 16;        // q-row base
    const int sl = tid & 127, hh = tid >> 7;  // staging: (s-local, head-group)

    const bool f32 = detect_f32<512>((const u16*)x, tid, redd);
    const float scale = 0.35355339059327373f;  // 1/sqrt(DK)

    // ---- Q fragments (A-layout direct): lane (lr,quad) holds
    // z(m0+lr, head=quad) for k=0..31 and z(m0+lr, head=quad+4) for k=32..63.
    half8v a0, a1;
    {
        float z[8];
        union { half8v v; _Float16 h[8]; } u;
        proj_compute(x, phi, f32, ((b << 10) + (m0 + lr)) * 8 + quad, z);
#pragma unroll
        for (int j = 0; j < 8; ++j) u.h[j] = (_Float16)z[j];
        a0 = u.v;
        proj_compute(x, phi, f32, ((b << 10) + (m0 + lr)) * 8 + quad + 4, z);
#pragma unroll
        for (int j = 0; j < 8; ++j) u.h[j] = (_Float16)z[j];
        a1 = u.v;
    }

    // ---- QK pass: 8 chunks of 128 keys.
    // Stage layout Kt3[e>>3][s_local][e&7]: addr=((h*128)+s)*8+j -> thread's
    // 8 e-contiguous z's form ONE b128 write, lane-contiguous (conflict-free).
    // B-frag read: lane (lr,quad) reads KV[(eblk*128 + w*16+lr)*8 ..+8] ->
    // lane-contiguous 16B (conflict-free).
#pragma unroll 1
    for (int ch = 0; ch < 8; ++ch) {
#pragma unroll
        for (int hp = 0; hp < 2; ++hp) {
            int h = hh + hp * 4;
            int s = ch * 128 + sl;
            float z[8];
            proj_compute(x, phi, f32, ((b << 10) + s) * 8 + h, z);
            union { half8v v; _Float16 hx[8]; } u;
#pragma unroll
            for (int j = 0; j < 8; ++j) u.hx[j] = (_Float16)z[j];
            *(half8v*)(&KV[(h * 128 + sl) * 8]) = u.v;
        }
        __syncthreads();
        {
            int s_local = wave * 16 + lr;
            half8v b0 = *(const half8v*)(&KV[(quad * 128 + s_local) * 8]);
            half8v b1 = *(const half8v*)(&KV[((quad + 4) * 128 + s_local) * 8]);
            floatx4 acc = {0.f, 0.f, 0.f, 0.f};
            acc = MFMA16(a0, b0, acc);
            acc = MFMA16(a1, b1, acc);
#pragma unroll
            for (int r = 0; r < 4; ++r) {
                int row = quad * 4 + r, col = ch * 128 + wave * 16 + lr;
                Stile[sidx(row, col >> 3) + (col & 7)] = (_Float16)(acc[r] * scale);
            }
        }
        __syncthreads();
    }

    // ---- exact softmax (R5-proven; 32 threads/row)
    {
        const int row = tid >> 5, seg = tid & 31;
        half8v hv[4];
#pragma unroll
        for (int i = 0; i < 4; ++i)
            hv[i] = *(const half8v*)(&Stile[sidx(row, i * 32 + seg)]);
        float mloc = -1e30f;
#pragma unroll
        for (int i = 0; i < 4; ++i)
#pragma unroll
            for (int j = 0; j < 8; ++j) mloc = fmaxf(mloc, (float)hv[i][j]);
#pragma unroll
        for (int off = 16; off > 0; off >>= 1)
            mloc = fmaxf(mloc, __shfl_xor(mloc, off, 64));
        float lsum = 0.f;
#pragma unroll
        for (int i = 0; i < 4; ++i) {
#pragma unroll
            for (int j = 0; j < 8; ++j) {
                float e = __expf((float)hv[i][j] - mloc);
                lsum += e;
                hv[i][j] = (_Float16)(e * 256.f);  // prescale vs fp16 denormals
            }
        }
#pragma unroll
        for (int off = 16; off > 0; off >>= 1)
            lsum += __shfl_xor(lsum, off, 64);
        if (seg == 0) rowsum[row] = lsum;
#pragma unroll
        for (int i = 0; i < 4; ++i)
            *(half8v*)(&Stile[sidx(row, i * 32 + seg)]) = hv[i];
    }
    __syncthreads();

    // ---- PV pass: ctx = P . V over 8 chunks. wave = (th = w>>2)x(eg = w&3).
    // Stage layout Vt3[t>>3][e][t&7]: B-frag lane (lr->e=eg*16+lr) reads
    // KV[((tblk)*64 + e)*8 ..+8] -> lane-contiguous 16B (conflict-free).
    // Staging writes are 8 scalar b16 with lane-rotation jr=(j+sl)&7 to
    // spread banks.
    const int th = wave >> 2, eg = wave & 3;
    floatx4 accA = {0.f, 0.f, 0.f, 0.f}, accB = {0.f, 0.f, 0.f, 0.f};
#pragma unroll 1
    for (int ch = 0; ch < 8; ++ch) {
#pragma unroll
        for (int hp = 0; hp < 2; ++hp) {
            int h = hh + hp * 4;
            int t = ch * 128 + sl;
            float z[8];
            proj_compute(x, phi, f32, ((b << 10) + t) * 8 + h, z);
            int tblk = sl >> 3, tin = sl & 7;
#pragma unroll
            for (int j = 0; j < 8; ++j) {
                int jr = (j + sl) & 7;
                KV[(tblk * 64 + h * 8 + jr) * 8 + tin] = (_Float16)z[jr];
            }
        }
        __syncthreads();
        {
            // MFMA0: t_local = th*64 + quad*8+j ; MFMA1: +32
            half8v B0 = *(const half8v*)(&KV[((th * 8 + quad) * 64 + eg * 16 + lr) * 8]);
            half8v B1 = *(const half8v*)(&KV[((th * 8 + 4 + quad) * 64 + eg * 16 + lr) * 8]);
            half8v A0 = *(const half8v*)(&Stile[sidx(lr, ch * 16 + th * 8 + quad)]);
            half8v A1 = *(const half8v*)(&Stile[sidx(lr, ch * 16 + th * 8 + 4 + quad)]);
            accA = MFMA16(A0, B0, accA);
            accB = MFMA16(A1, B1, accB);
        }
        __syncthreads();
    }
    floatx4 accT = accA + accB;

    // th-pair reduce via pacc, then normalize into ctx_lds
    if (th == 1) {
#pragma unroll
        for (int r = 0; r < 4; ++r) pacc[eg][quad * 4 + r][lr] = accT[r];
    }
    __syncthreads();
    if (th == 0) {
#pragma unroll
        for (int r = 0; r < 4; ++r) {
            int row_l = quad * 4 + r;
            float inv = 1.0f / (256.0f * rowsum[row_l]);
            ctx_lds[row_l][eg * 16 + lr] =
                (_Float16)((accT[r] + pacc[eg][row_l][lr]) * inv);
        }
    }
    __syncthreads();

    // ---- epilogue: out = ctx @ W^T + bias (waves 0-3)
    if (wave < 4) {
        const int o = wave * 16 + lr;
        half8v ca0 = *(const half8v*)(&ctx_lds[lr][quad * 8]);
        half8v ca1 = *(const half8v*)(&ctx_lds[lr][32 + quad * 8]);
        half8v wb0, wb1;
        if (f32) {
            const float* wr = (const float*)Wp + (size_t)o * EE;
            union { half8v v; _Float16 h[8]; } w0, w1;
#pragma unroll
            for (int j = 0; j < 8; ++j) {
                w0.h[j] = (_Float16)wr[quad * 8 + j];
                w1.h[j] = (_Float16)wr[32 + quad * 8 + j];
            }
            wb0 = w0.v; wb1 = w1.v;
        } else {
            const bf16* wr = (const bf16*)Wp + (size_t)o * EE;
            union { uint4 u; bf16 hv[8]; } r0, r1;
            r0.u = *(const uint4*)(wr + quad * 8);
            r1.u = *(const uint4*)(wr + 32 + quad * 8);
            union { half8v v; _Float16 h[8]; } w0, w1;
#pragma unroll
            for (int j = 0; j < 8; ++j) {
                w0.h[j] = (_Float16)__bfloat162float(r0.hv[j]);
                w1.h[j] = (_Float16)__bfloat162float(r1.hv[j]);
            }
            wb0 = w0.v; wb1 = w1.v;
        }
        floatx4 oacc = {0.f, 0.f, 0.f, 0.f};
        oacc = MFMA16(ca0, wb0, oacc);
        oacc = MFMA16(ca1, wb1, oacc);

        float bo = f32 ? ((const float*)biasp)[o]
                       : __bfloat162float(((const bf16*)biasp)[o]);
#pragma unroll
        for (int r = 0; r < 4; ++r) {
            size_t oi = ((size_t)b * SS + m0 + quad * 4 + r) * EE + o;
            float val = oacc[r] + bo;
            if (f32) ((float*)outp)[oi] = val;
            else     ((bf16*)outp)[oi] = __float2bfloat16(val);
        }
    }
}

// ---------------------------------------------------------------------------
extern "C" void kernel_launch(void* const* d_in, const int* in_sizes, int n_in,
                              void* d_out, int out_size, void* d_ws, size_t ws_size,
                              hipStream_t stream) {
    const void* x    = d_in[0];
    const void* phi  = d_in[1];
    const void* W    = d_in[2];
    const void* bias = d_in[3];
    (void)d_ws; (void)ws_size;

    qflash<<<dim3(512), dim3(512), 0, stream>>>(x, phi, W, bias, d_out);
}

// Round 9
// 82.856 us; speedup vs baseline: 1.3290x; 1.3290x over previous
//
#include <hip/hip_runtime.h>
#include <hip/hip_bf16.h>

// Problem constants (from reference): B=8, S=1024, E=64, H=8, DK=8
#define BB 8
#define SS 1024
#define EE 64
#define HH 8
#define DKW 8

typedef __hip_bfloat16 bf16;
typedef unsigned short u16;
typedef _Float16 half8v __attribute__((ext_vector_type(8)));
typedef float floatx4 __attribute__((ext_vector_type(4)));

#define MFMA16(a, b, c) __builtin_amdgcn_mfma_f32_16x16x32_f16(a, b, c, 0, 0, 0)

// d_ws layout: [0,1MB) projH fp16 [B][S][E]; [1MB,2MB) projT fp16 [B][E][S]
#define OFF_PROJT ((size_t)BB * SS * EE * 2)

// ---------------------------------------------------------------------------
// Block-uniform dtype self-detection (R4-R8 proven): if `base` really holds
// float32, even-indexed u16s are random f32 mantissa bits -> ~48% decode (as
// bf16) to |v| >= 32; genuine bf16 N(0,1) -> ~0. Deterministic per buffer.
template <int NT>
__device__ __forceinline__ bool detect_f32(const u16* __restrict__ base,
                                           int tid, int* red) {
    int cnt = 0;
    for (int i = tid; i < 2048; i += NT) {
        u16 u = base[i * 2];
        int ex = (u >> 7) & 0xFF;
        cnt += (ex >= 0x84) ? 1 : 0;
    }
#pragma unroll
    for (int off = 32; off > 0; off >>= 1) cnt += __shfl_xor(cnt, off, 64);
    if ((tid & 63) == 0) red[tid >> 6] = cnt;
    __syncthreads();
    int tot = 0;
#pragma unroll
    for (int w = 0; w < NT / 64; ++w) tot += red[w];
    return tot > 64;
}

// ---------------------------------------------------------------------------
// Analytic quantum projection (R0 derivation, verified R2-R8):
//   Z_0 = prod_{j=1..7} cos(theta_j);  Z_w = prod_{j=0..w} cos(theta_j)
__device__ __forceinline__ void proj_compute(const void* x, const void* phi,
                                             bool f32, int m, float* z) {
    int h = m & (HH - 1);
    float th[DKW];
    if (f32) {
        const float4* xp = (const float4*)((const float*)x + (size_t)m * DKW);
        const float4* pp = (const float4*)((const float*)phi + h * DKW);
        float4 x0 = xp[0], x1 = xp[1];
        float4 p0 = pp[0], p1 = pp[1];
        th[0] = x0.x + p0.x; th[1] = x0.y + p0.y; th[2] = x0.z + p0.z; th[3] = x0.w + p0.w;
        th[4] = x1.x + p1.x; th[5] = x1.y + p1.y; th[6] = x1.z + p1.z; th[7] = x1.w + p1.w;
    } else {
        union { uint4 u; bf16 hv[8]; } xu, pu;
        xu.u = *(const uint4*)((const bf16*)x + (size_t)m * DKW);
        pu.u = *(const uint4*)((const bf16*)phi + (size_t)h * DKW);
#pragma unroll
        for (int j = 0; j < DKW; ++j)
            th[j] = __bfloat162float(xu.hv[j]) + __bfloat162float(pu.hv[j]);
    }
    float c[DKW];
#pragma unroll
    for (int j = 0; j < DKW; ++j) c[j] = __cosf(th[j]);
    float suf = c[1];
#pragma unroll
    for (int j = 2; j < DKW; ++j) suf *= c[j];
    z[0] = suf;
    float pre = c[0];
#pragma unroll
    for (int w = 1; w < DKW; ++w) { pre *= c[w]; z[w] = pre; }
}

// ---------------------------------------------------------------------------
// Projection: fp16 projH [b][s][e] + projT [b][e][s] via LDS-staged transpose.
__global__ __launch_bounds__(256) void proj_f16_kernel(const void* __restrict__ x,
                                                       const void* __restrict__ phi,
                                                       _Float16* __restrict__ projH,
                                                       _Float16* __restrict__ projT) {
    __shared__ int redd[4];
    __shared__ _Float16 zt[EE][40];
    const int tid = threadIdx.x;
    const bool f32 = detect_f32<256>((const u16*)x, tid, redd);

    const int m = blockIdx.x * 256 + tid;  // (b*S + s)*H + h
    float z[DKW];
    proj_compute(x, phi, f32, m, z);

    union { half8v v; _Float16 h[8]; } o;
#pragma unroll
    for (int j = 0; j < DKW; ++j) o.h[j] = (_Float16)z[j];
    *(half8v*)(projH + (size_t)m * DKW) = o.v;

    const int h = m & (HH - 1);
    const int sl = (tid >> 3) & 31;
#pragma unroll
    for (int j = 0; j < DKW; ++j) zt[h * DKW + j][sl] = o.h[j];
    __syncthreads();

    const int b = blockIdx.x >> 5;
    const int s0 = (blockIdx.x * 32) & (SS - 1);
    const int row = tid >> 2, ch = tid & 3;
    half8v vv = *(const half8v*)(&zt[row][ch * 8]);
    *(half8v*)(projT + ((size_t)(b * EE + row)) * SS + s0 + ch * 8) = vv;
}

// ---------------------------------------------------------------------------
// Fused attention: 32 q-rows/block (halves redundant L2 slab traffic vs the
// 16-row R5 version), 512 thr (8 waves), grid 256 blocks = 1 block/CU.
// Stile: flat 32x1024 fp16 XOR-swizzled (R5-proven conflict-free paths).
__device__ __forceinline__ int sidx(int row, int colblk) {
    return row * 1024 + ((colblk ^ (row & 7)) << 3);
}

__global__ __launch_bounds__(512) void fused_attn(const _Float16* __restrict__ projH,
                                                  const _Float16* __restrict__ projT,
                                                  const void* __restrict__ Wp,
                                                  const void* __restrict__ biasp,
                                                  void* __restrict__ outp) {
    __shared__ _Float16 Stile[32 * 1024];   // 64 KB, swizzled
    __shared__ _Float16 ctx_lds[32][72];    // 4.6 KB
    __shared__ float    rowsum[32];
    __shared__ int      redd[8];

    const int tid = threadIdx.x;
    const int wave = tid >> 6, lane = tid & 63;
    const int lr = lane & 15, quad = lane >> 4;
    const int bid = blockIdx.x;
    const int b = bid & 7;                  // XCD-pinned batch
    const int m0 = (bid >> 3) * 32;         // q-row base (32 tiles/batch)

    const bool f32 = detect_f32<512>((const u16*)Wp, tid, redd);

    const _Float16* Pb = projH + (size_t)b * SS * EE;
    const float scale = 0.35355339059327373f;  // 1/sqrt(DK)

    // ---- phase 1: S = scale * Q . K^T -> Stile.
    // Per wave: 128-col strip; A-frags for row-sets 0-15 and 16-31 share the
    // B-frag loads (the key traffic saving of the 32-row tile).
    {
        const _Float16* ar0 = Pb + (size_t)(m0 + lr) * EE;
        const _Float16* ar1 = Pb + (size_t)(m0 + 16 + lr) * EE;
        half8v a0 = *(const half8v*)(ar0 + quad * 8);
        half8v a1 = *(const half8v*)(ar0 + 32 + quad * 8);
        half8v a2 = *(const half8v*)(ar1 + quad * 8);
        half8v a3 = *(const half8v*)(ar1 + 32 + quad * 8);
#pragma unroll 2
        for (int c = 0; c < 8; ++c) {
            int n = wave * 128 + c * 16;
            const _Float16* brow = Pb + (size_t)(n + lr) * EE;
            half8v b0 = *(const half8v*)(brow + quad * 8);
            half8v b1 = *(const half8v*)(brow + 32 + quad * 8);
            floatx4 acc0 = {0.f, 0.f, 0.f, 0.f};
            floatx4 acc1 = {0.f, 0.f, 0.f, 0.f};
            acc0 = MFMA16(a0, b0, acc0);
            acc0 = MFMA16(a1, b1, acc0);
            acc1 = MFMA16(a2, b0, acc1);
            acc1 = MFMA16(a3, b1, acc1);
            int colblk = (n + lr) >> 3, cin = (n + lr) & 7;
#pragma unroll
            for (int r = 0; r < 4; ++r) {
                Stile[sidx(quad * 4 + r, colblk) + cin]      = (_Float16)(acc0[r] * scale);
                Stile[sidx(16 + quad * 4 + r, colblk) + cin] = (_Float16)(acc1[r] * scale);
            }
        }
    }
    __syncthreads();

    // ---- phase 2: exact softmax; 16 threads/row, seg-contiguous b128 chunks
    // (swizzle is a within-row permutation -> max/sum unaffected).
    {
        const int row = tid >> 4, seg = tid & 15;
        half8v hv[8];
#pragma unroll
        for (int i = 0; i < 8; ++i)
            hv[i] = *(const half8v*)(&Stile[sidx(row, i * 16 + seg)]);
        float mloc = -1e30f;
#pragma unroll
        for (int i = 0; i < 8; ++i)
#pragma unroll
            for (int j = 0; j < 8; ++j) mloc = fmaxf(mloc, (float)hv[i][j]);
#pragma unroll
        for (int off = 8; off > 0; off >>= 1)
            mloc = fmaxf(mloc, __shfl_xor(mloc, off, 64));
        float lsum = 0.f;
#pragma unroll
        for (int i = 0; i < 8; ++i) {
#pragma unroll
            for (int j = 0; j < 8; ++j) {
                float e = __expf((float)hv[i][j] - mloc);
                lsum += e;
                hv[i][j] = (_Float16)(e * 256.f);  // prescale vs fp16 denormals
            }
        }
#pragma unroll
        for (int off = 8; off > 0; off >>= 1)
            lsum += __shfl_xor(lsum, off, 64);
        if (seg == 0) rowsum[row] = lsum;
#pragma unroll
        for (int i = 0; i < 8; ++i)
            *(half8v*)(&Stile[sidx(row, i * 16 + seg)]) = hv[i];
    }
    __syncthreads();

    // ---- phase 3: ctx = P . V. wave = (rowg = w>>2) x (eg = w&3);
    // each wave: 16 rows x 16 e-cols over full K=1024 (32 MFMAs).
    const int rowg = wave >> 2, eg = wave & 3;
    {
        const int e = eg * 16 + lr;
        const _Float16* vrow = projT + ((size_t)(b * EE + e)) * SS;
        floatx4 acc = {0.f, 0.f, 0.f, 0.f};
#pragma unroll 4
        for (int k0 = 0; k0 < SS; k0 += 32) {
            half8v A = *(const half8v*)(&Stile[sidx(rowg * 16 + lr, (k0 >> 3) + quad)]);
            half8v B = *(const half8v*)(vrow + k0 + quad * 8);
            acc = MFMA16(A, B, acc);
        }
#pragma unroll
        for (int r = 0; r < 4; ++r) {
            int row_l = rowg * 16 + quad * 4 + r;
            float inv = 1.0f / (256.0f * rowsum[row_l]);
            ctx_lds[row_l][eg * 16 + lr] = (_Float16)(acc[r] * inv);
        }
    }
    __syncthreads();

    // ---- phase 4: out = ctx @ W^T + bias (all 8 waves; rowg x eg tiling)
    {
        const int o = eg * 16 + lr;
        half8v ca0 = *(const half8v*)(&ctx_lds[rowg * 16 + lr][quad * 8]);
        half8v ca1 = *(const half8v*)(&ctx_lds[rowg * 16 + lr][32 + quad * 8]);
        half8v wb0, wb1;
        if (f32) {
            const float* wr = (const float*)Wp + (size_t)o * EE;
            union { half8v v; _Float16 h[8]; } w0, w1;
#pragma unroll
            for (int j = 0; j < 8; ++j) {
                w0.h[j] = (_Float16)wr[quad * 8 + j];
                w1.h[j] = (_Float16)wr[32 + quad * 8 + j];
            }
            wb0 = w0.v; wb1 = w1.v;
        } else {
            const bf16* wr = (const bf16*)Wp + (size_t)o * EE;
            union { uint4 u; bf16 hv[8]; } r0, r1;
            r0.u = *(const uint4*)(wr + quad * 8);
            r1.u = *(const uint4*)(wr + 32 + quad * 8);
            union { half8v v; _Float16 h[8]; } w0, w1;
#pragma unroll
            for (int j = 0; j < 8; ++j) {
                w0.h[j] = (_Float16)__bfloat162float(r0.hv[j]);
                w1.h[j] = (_Float16)__bfloat162float(r1.hv[j]);
            }
            wb0 = w0.v; wb1 = w1.v;
        }
        floatx4 oacc = {0.f, 0.f, 0.f, 0.f};
        oacc = MFMA16(ca0, wb0, oacc);
        oacc = MFMA16(ca1, wb1, oacc);

        float bo = f32 ? ((const float*)biasp)[o]
                       : __bfloat162float(((const bf16*)biasp)[o]);
#pragma unroll
        for (int r = 0; r < 4; ++r) {
            size_t oi = ((size_t)b * SS + m0 + rowg * 16 + quad * 4 + r) * EE + o;
            float val = oacc[r] + bo;
            if (f32) ((float*)outp)[oi] = val;
            else     ((bf16*)outp)[oi] = __float2bfloat16(val);
        }
    }
}

// ---------------------------------------------------------------------------
extern "C" void kernel_launch(void* const* d_in, const int* in_sizes, int n_in,
                              void* d_out, int out_size, void* d_ws, size_t ws_size,
                              hipStream_t stream) {
    const void* x    = d_in[0];
    const void* phi  = d_in[1];
    const void* W    = d_in[2];
    const void* bias = d_in[3];

    _Float16* projH = (_Float16*)d_ws;
    _Float16* projT = (_Float16*)((char*)d_ws + OFF_PROJT);

    proj_f16_kernel<<<dim3(BB * SS * HH / 256), dim3(256), 0, stream>>>(x, phi, projH, projT);
    fused_attn<<<dim3(256), dim3(512), 0, stream>>>(projH, projT, W, bias, d_out);
}

// Round 10
// 77.771 us; speedup vs baseline: 1.4159x; 1.0654x over previous
//
#include <hip/hip_runtime.h>
#include <hip/hip_bf16.h>

// Problem constants (from reference): B=8, S=1024, E=64, H=8, DK=8
#define BB 8
#define SS 1024
#define EE 64
#define HH 8
#define DKW 8

typedef __hip_bfloat16 bf16;
typedef unsigned short u16;
typedef _Float16 half8v __attribute__((ext_vector_type(8)));
typedef float floatx4 __attribute__((ext_vector_type(4)));

#define MFMA16(a, b, c) __builtin_amdgcn_mfma_f32_16x16x32_f16(a, b, c, 0, 0, 0)

// d_ws layout: [0,1MB) projH fp16 [B][S][E]; [1MB,2MB) projT fp16 [B][E][S]
#define OFF_PROJT ((size_t)BB * SS * EE * 2)

// ---------------------------------------------------------------------------
// Block-uniform dtype self-detection (R4-R9 proven): if `base` really holds
// float32, even-indexed u16s are random f32 mantissa bits -> ~48% decode (as
// bf16) to |v| >= 32; genuine bf16 N(0,1) -> ~0. Deterministic per buffer.
template <int NT>
__device__ __forceinline__ bool detect_f32(const u16* __restrict__ base,
                                           int tid, int* red) {
    int cnt = 0;
    for (int i = tid; i < 2048; i += NT) {
        u16 u = base[i * 2];
        int ex = (u >> 7) & 0xFF;
        cnt += (ex >= 0x84) ? 1 : 0;
    }
#pragma unroll
    for (int off = 32; off > 0; off >>= 1) cnt += __shfl_xor(cnt, off, 64);
    if ((tid & 63) == 0) red[tid >> 6] = cnt;
    __syncthreads();
    int tot = 0;
#pragma unroll
    for (int w = 0; w < NT / 64; ++w) tot += red[w];
    return tot > 64;
}

// ---------------------------------------------------------------------------
// Analytic quantum projection (R0 derivation, verified R2-R9):
//   Z_0 = prod_{j=1..7} cos(theta_j);  Z_w = prod_{j=0..w} cos(theta_j)
__device__ __forceinline__ void proj_compute(const void* x, const void* phi,
                                             bool f32, int m, float* z) {
    int h = m & (HH - 1);
    float th[DKW];
    if (f32) {
        const float4* xp = (const float4*)((const float*)x + (size_t)m * DKW);
        const float4* pp = (const float4*)((const float*)phi + h * DKW);
        float4 x0 = xp[0], x1 = xp[1];
        float4 p0 = pp[0], p1 = pp[1];
        th[0] = x0.x + p0.x; th[1] = x0.y + p0.y; th[2] = x0.z + p0.z; th[3] = x0.w + p0.w;
        th[4] = x1.x + p1.x; th[5] = x1.y + p1.y; th[6] = x1.z + p1.z; th[7] = x1.w + p1.w;
    } else {
        union { uint4 u; bf16 hv[8]; } xu, pu;
        xu.u = *(const uint4*)((const bf16*)x + (size_t)m * DKW);
        pu.u = *(const uint4*)((const bf16*)phi + (size_t)h * DKW);
#pragma unroll
        for (int j = 0; j < DKW; ++j)
            th[j] = __bfloat162float(xu.hv[j]) + __bfloat162float(pu.hv[j]);
    }
    float c[DKW];
#pragma unroll
    for (int j = 0; j < DKW; ++j) c[j] = __cosf(th[j]);
    float suf = c[1];
#pragma unroll
    for (int j = 2; j < DKW; ++j) suf *= c[j];
    z[0] = suf;
    float pre = c[0];
#pragma unroll
    for (int w = 1; w < DKW; ++w) { pre *= c[w]; z[w] = pre; }
}

// ---------------------------------------------------------------------------
// Projection: fp16 projH [b][s][e] + projT [b][e][s] via LDS-staged transpose.
__global__ __launch_bounds__(256) void proj_f16_kernel(const void* __restrict__ x,
                                                       const void* __restrict__ phi,
                                                       _Float16* __restrict__ projH,
                                                       _Float16* __restrict__ projT) {
    __shared__ int redd[4];
    __shared__ _Float16 zt[EE][40];
    const int tid = threadIdx.x;
    const bool f32 = detect_f32<256>((const u16*)x, tid, redd);

    const int m = blockIdx.x * 256 + tid;  // (b*S + s)*H + h
    float z[DKW];
    proj_compute(x, phi, f32, m, z);

    union { half8v v; _Float16 h[8]; } o;
#pragma unroll
    for (int j = 0; j < DKW; ++j) o.h[j] = (_Float16)z[j];
    *(half8v*)(projH + (size_t)m * DKW) = o.v;

    const int h = m & (HH - 1);
    const int sl = (tid >> 3) & 31;
#pragma unroll
    for (int j = 0; j < DKW; ++j) zt[h * DKW + j][sl] = o.h[j];
    __syncthreads();

    const int b = blockIdx.x >> 5;
    const int s0 = (blockIdx.x * 32) & (SS - 1);
    const int row = tid >> 2, ch = tid & 3;
    half8v vv = *(const half8v*)(&zt[row][ch * 8]);
    *(half8v*)(projT + ((size_t)(b * EE + row)) * SS + s0 + ch * 8) = vv;
}

// ---------------------------------------------------------------------------
// Fused attention (R9 base + W-prefetch + phase-3 K-split):
// 32 q-rows/block, 512 thr (8 waves), grid 256 blocks, XCD-pinned batches.
__device__ __forceinline__ int sidx(int row, int colblk) {
    return row * 1024 + ((colblk ^ (row & 7)) << 3);  // XOR-swizzled 32x1024
}

__global__ __launch_bounds__(512) void fused_attn(const _Float16* __restrict__ projH,
                                                  const _Float16* __restrict__ projT,
                                                  const void* __restrict__ Wp,
                                                  const void* __restrict__ biasp,
                                                  void* __restrict__ outp) {
    __shared__ _Float16 Stile[32 * 1024];   // 64 KB, swizzled
    __shared__ float    pacc[4][32][17];    // 8.7 KB K-split partials
    __shared__ _Float16 ctx_lds[32][72];    // 4.6 KB
    __shared__ float    rowsum[32];
    __shared__ int      redd[8];

    const int tid = threadIdx.x;
    const int wave = tid >> 6, lane = tid & 63;
    const int lr = lane & 15, quad = lane >> 4;
    const int bid = blockIdx.x;
    const int b = bid & 7;                  // XCD-pinned batch
    const int m0 = (bid >> 3) * 32;         // q-row base

    const bool f32 = detect_f32<512>((const u16*)Wp, tid, redd);

    // ---- W/bias prefetch: issue phase-4's global loads NOW so their L2
    // latency hides under phases 1-3 (they were previously issued after
    // three barriers, fully exposed at the block's tail).
    const int o_out = (wave & 3) * 16 + lr;
    half8v wb0, wb1;
    float bo;
    {
        if (f32) {
            const float* wr = (const float*)Wp + (size_t)o_out * EE;
            union { half8v v; _Float16 h[8]; } w0, w1;
#pragma unroll
            for (int j = 0; j < 8; ++j) {
                w0.h[j] = (_Float16)wr[quad * 8 + j];
                w1.h[j] = (_Float16)wr[32 + quad * 8 + j];
            }
            wb0 = w0.v; wb1 = w1.v;
            bo = ((const float*)biasp)[o_out];
        } else {
            const bf16* wr = (const bf16*)Wp + (size_t)o_out * EE;
            union { uint4 u; bf16 hv[8]; } r0, r1;
            r0.u = *(const uint4*)(wr + quad * 8);
            r1.u = *(const uint4*)(wr + 32 + quad * 8);
            union { half8v v; _Float16 h[8]; } w0, w1;
#pragma unroll
            for (int j = 0; j < 8; ++j) {
                w0.h[j] = (_Float16)__bfloat162float(r0.hv[j]);
                w1.h[j] = (_Float16)__bfloat162float(r1.hv[j]);
            }
            wb0 = w0.v; wb1 = w1.v;
            bo = __bfloat162float(((const bf16*)biasp)[o_out]);
        }
    }

    const _Float16* Pb = projH + (size_t)b * SS * EE;
    const float scale = 0.35355339059327373f;  // 1/sqrt(DK)

    // ---- phase 1: S = scale * Q . K^T -> Stile. Per wave: 128-col strip;
    // both 16-row sets share the B-frag loads.
    {
        const _Float16* ar0 = Pb + (size_t)(m0 + lr) * EE;
        const _Float16* ar1 = Pb + (size_t)(m0 + 16 + lr) * EE;
        half8v a0 = *(const half8v*)(ar0 + quad * 8);
        half8v a1 = *(const half8v*)(ar0 + 32 + quad * 8);
        half8v a2 = *(const half8v*)(ar1 + quad * 8);
        half8v a3 = *(const half8v*)(ar1 + 32 + quad * 8);
#pragma unroll 2
        for (int c = 0; c < 8; ++c) {
            int n = wave * 128 + c * 16;
            const _Float16* brow = Pb + (size_t)(n + lr) * EE;
            half8v b0 = *(const half8v*)(brow + quad * 8);
            half8v b1 = *(const half8v*)(brow + 32 + quad * 8);
            floatx4 acc0 = {0.f, 0.f, 0.f, 0.f};
            floatx4 acc1 = {0.f, 0.f, 0.f, 0.f};
            acc0 = MFMA16(a0, b0, acc0);
            acc0 = MFMA16(a1, b1, acc0);
            acc1 = MFMA16(a2, b0, acc1);
            acc1 = MFMA16(a3, b1, acc1);
            int colblk = (n + lr) >> 3, cin = (n + lr) & 7;
#pragma unroll
            for (int r = 0; r < 4; ++r) {
                Stile[sidx(quad * 4 + r, colblk) + cin]      = (_Float16)(acc0[r] * scale);
                Stile[sidx(16 + quad * 4 + r, colblk) + cin] = (_Float16)(acc1[r] * scale);
            }
        }
    }
    __syncthreads();

    // ---- phase 2: exact softmax; 16 threads/row, b128 chunks (swizzle is a
    // within-row permutation -> max/sum unaffected).
    {
        const int row = tid >> 4, seg = tid & 15;
        half8v hv[8];
#pragma unroll
        for (int i = 0; i < 8; ++i)
            hv[i] = *(const half8v*)(&Stile[sidx(row, i * 16 + seg)]);
        float mloc = -1e30f;
#pragma unroll
        for (int i = 0; i < 8; ++i)
#pragma unroll
            for (int j = 0; j < 8; ++j) mloc = fmaxf(mloc, (float)hv[i][j]);
#pragma unroll
        for (int off = 8; off > 0; off >>= 1)
            mloc = fmaxf(mloc, __shfl_xor(mloc, off, 64));
        float lsum = 0.f;
#pragma unroll
        for (int i = 0; i < 8; ++i) {
#pragma unroll
            for (int j = 0; j < 8; ++j) {
                float e = __expf((float)hv[i][j] - mloc);
                lsum += e;
                hv[i][j] = (_Float16)(e * 256.f);  // prescale vs fp16 denormals
            }
        }
#pragma unroll
        for (int off = 8; off > 0; off >>= 1)
            lsum += __shfl_xor(lsum, off, 64);
        if (seg == 0) rowsum[row] = lsum;
#pragma unroll
        for (int i = 0; i < 8; ++i)
            *(half8v*)(&Stile[sidx(row, i * 16 + seg)]) = hv[i];
    }
    __syncthreads();

    // ---- phase 3: ctx = P . V, K-SPLIT across waves: wave = (kh = w>>2) x
    // (eg = w&3). Each wave does K=512 for all 32 rows x 16 e-cols -> V rows
    // read once per block (halved projT traffic vs row-split), dependent
    // MFMA chains halved (16 per acc). kh-pairs reduce via pacc.
    const int kh = wave >> 2, eg = wave & 3;
    {
        const int e = eg * 16 + lr;
        const _Float16* vrow = projT + ((size_t)(b * EE + e)) * SS + kh * 512;
        floatx4 acc0 = {0.f, 0.f, 0.f, 0.f};   // rows 0-15
        floatx4 acc1 = {0.f, 0.f, 0.f, 0.f};   // rows 16-31
#pragma unroll 4
        for (int k0 = 0; k0 < 512; k0 += 32) {
            int kb = ((kh * 512 + k0) >> 3) + quad;
            half8v B  = *(const half8v*)(vrow + k0 + quad * 8);
            half8v A0 = *(const half8v*)(&Stile[sidx(lr, kb)]);
            half8v A1 = *(const half8v*)(&Stile[sidx(16 + lr, kb)]);
            acc0 = MFMA16(A0, B, acc0);
            acc1 = MFMA16(A1, B, acc1);
        }
        if (kh == 1) {
#pragma unroll
            for (int r = 0; r < 4; ++r) {
                pacc[eg][quad * 4 + r][lr]      = acc0[r];
                pacc[eg][16 + quad * 4 + r][lr] = acc1[r];
            }
        }
        __syncthreads();
        if (kh == 0) {
#pragma unroll
            for (int r = 0; r < 4; ++r) {
                int r0 = quad * 4 + r, r1 = 16 + quad * 4 + r;
                float inv0 = 1.0f / (256.0f * rowsum[r0]);
                float inv1 = 1.0f / (256.0f * rowsum[r1]);
                ctx_lds[r0][e] = (_Float16)((acc0[r] + pacc[eg][r0][lr]) * inv0);
                ctx_lds[r1][e] = (_Float16)((acc1[r] + pacc[eg][r1][lr]) * inv1);
            }
        }
    }
    __syncthreads();

    // ---- phase 4: out = ctx @ W^T + bias (all 8 waves; rowg x eg tiling;
    // W/bias already in registers from the entry prefetch).
    {
        const int rowg = wave >> 2;
        half8v ca0 = *(const half8v*)(&ctx_lds[rowg * 16 + lr][quad * 8]);
        half8v ca1 = *(const half8v*)(&ctx_lds[rowg * 16 + lr][32 + quad * 8]);
        floatx4 oacc = {0.f, 0.f, 0.f, 0.f};
        oacc = MFMA16(ca0, wb0, oacc);
        oacc = MFMA16(ca1, wb1, oacc);
#pragma unroll
        for (int r = 0; r < 4; ++r) {
            size_t oi = ((size_t)b * SS + m0 + rowg * 16 + quad * 4 + r) * EE + o_out;
            float val = oacc[r] + bo;
            if (f32) ((float*)outp)[oi] = val;
            else     ((bf16*)outp)[oi] = __float2bfloat16(val);
        }
    }
}

// ---------------------------------------------------------------------------
extern "C" void kernel_launch(void* const* d_in, const int* in_sizes, int n_in,
                              void* d_out, int out_size, void* d_ws, size_t ws_size,
                              hipStream_t stream) {
    const void* x    = d_in[0];
    const void* phi  = d_in[1];
    const void* W    = d_in[2];
    const void* bias = d_in[3];

    _Float16* projH = (_Float16*)d_ws;
    _Float16* projT = (_Float16*)((char*)d_ws + OFF_PROJT);

    proj_f16_kernel<<<dim3(BB * SS * HH / 256), dim3(256), 0, stream>>>(x, phi, projH, projT);
    fused_attn<<<dim3(256), dim3(512), 0, stream>>>(projH, projT, W, bias, d_out);
}